// Round 16
// baseline (796.648 us; speedup 1.0000x reference)
//
#include <hip/hip_runtime.h>

typedef unsigned short u16;
typedef unsigned int   u32;
typedef __attribute__((ext_vector_type(8))) short bf16x8;
typedef __attribute__((ext_vector_type(4))) float f32x4;

__device__ __forceinline__ float b2f(u16 u) {
    union { u32 i; float f; } v; v.i = ((u32)u) << 16; return v.f;
}
__device__ __forceinline__ u16 f2b(float f) {
    union { float f; u32 i; } v; v.f = f;
    u32 x = v.i;
    return (u16)((x + 0x7fffu + ((x >> 16) & 1u)) >> 16);
}
// dtype-agnostic parameter read: bf=1 -> bf16 source, bf=0 -> f32 source
__device__ __forceinline__ float ldf(const void* p, size_t i, int bf) {
    return bf ? b2f(((const u16*)p)[i]) : ((const float*)p)[i];
}

// ---------------------------------------------------------------------------
// Precompute per-layer scan constants; detect dtype; verify A structure;
// also materialize block_norm_w as f32 (4x512) for the fused rms-GEMM staging.
// flag[0]=dtype (bf16?), flag[1]=A-structured (cleared on mismatch).
// ---------------------------------------------------------------------------
__global__ __launch_bounds__(256)
void prep_k(const void* __restrict__ alog, const void* __restrict__ dsk,
            const void* __restrict__ normw, const void* __restrict__ bnw,
            float* __restrict__ a2f, float* __restrict__ df,
            float* __restrict__ bnwf, int* __restrict__ flag)
{
    const int bf = (((const u16*)normw)[0] == 0x3F80u) ? 1 : 0;
    const int t = blockIdx.x * 256 + threadIdx.x;
    if (t == 0) { flag[0] = bf; flag[1] = 1; }
    const float v = -expf(ldf(alog, t, bf)) * 1.44269504f;
    a2f[t] = v;
    const float base = -expf(ldf(alog, t & ~15, bf)) * 1.44269504f;
    const float expect = (float)((t & 15) + 1) * base;
    if (fabsf(v - expect) > 1e-4f * fabsf(expect) + 1e-7f)
        atomicAnd(&flag[1], 0);
    if (t < 4096) df[t] = ldf(dsk, t, bf);
    if (t < 2048) bnwf[t] = ldf(bnw, t, bf);
}

// ---------------------------------------------------------------------------
// Per-row RMS scale only: rs[row] = rsqrt(mean(x[row]^2)+eps).
// 4 waves/block, one wave per row (8 floats/lane).
// ---------------------------------------------------------------------------
__global__ __launch_bounds__(256)
void rscale_k(const float* __restrict__ x, float* __restrict__ rs)
{
    const int wave = threadIdx.x >> 6, lane = threadIdx.x & 63;
    const int row = blockIdx.x * 4 + wave;
    const float* xp = x + (size_t)row * 512 + lane * 8;
    const float4 v0 = *reinterpret_cast<const float4*>(xp);
    const float4 v1 = *reinterpret_cast<const float4*>(xp + 4);
    float ss = v0.x*v0.x + v0.y*v0.y + v0.z*v0.z + v0.w*v0.w
             + v1.x*v1.x + v1.y*v1.y + v1.z*v1.z + v1.w*v1.w;
    #pragma unroll
    for (int off = 32; off >= 1; off >>= 1) ss += __shfl_xor(ss, off);
    if (lane == 0) rs[row] = rsqrtf(ss * (1.f / 512.f) + 1e-6f);
}

// ===========================================================================
// BMx128x64 bf16 MFMA GEMM, global_load_lds B-staging, XOR-swizzled LDS,
// XCD-aware block remap. ASCALE=1: A comes from f32 x with fused RMSNorm
// (val * rs[row] * wn[col]) staged manually into the SAME swizzled layout.
// EPI: 0 = bf16 store (C2), 1 = f32 += (C)
// ===========================================================================
template<int BM, int EPI, int ASCALE = 0>
__global__ __launch_bounds__(256)
void gemm_gld_k(const u16* __restrict__ A, int lda,
                const u16* __restrict__ Bt, int K,
                float* __restrict__ C, int ldc,
                u16* __restrict__ C2,
                const float* __restrict__ Ax = nullptr,
                const float* __restrict__ rs = nullptr,
                const float* __restrict__ wn = nullptr)
{
    __shared__ __align__(16) u16 As[BM * 64];
    __shared__ __align__(16) u16 Bs[128 * 64];

    const int tid = threadIdx.x;
    const int NX = gridDim.x, NY = gridDim.y;
    const int bid = blockIdx.y * NX + blockIdx.x;
    const int xcd = bid & 7, j = bid >> 3;
    const int m_idx = xcd * (NY >> 3) + j / NX;
    const int n_idx = j % NX;
    const int m0 = m_idx * BM, n0 = n_idx * 128;

    const int lane = tid & 63, wave = tid >> 6;
    const int wr = wave >> 1, wc = wave & 1;
    constexpr int WM = BM / 2, FM = WM / 16;
    constexpr int AJ = BM / 32;

    const int lr = lane >> 3;
    const int skc = (lane & 7) ^ lr;

    f32x4 acc[FM][4] = {};

    for (int k0 = 0; k0 < K; k0 += 64) {
        if constexpr (ASCALE) {
            // manual A staging with fused rmsnorm; swizzled write
            constexpr int AC = (BM * 64) / 2048;   // 8-elem chunks per thread
            #pragma unroll
            for (int i = 0; i < AC; ++i) {
                const int idx = tid + i * 256;
                const int row = idx >> 3, kc = idx & 7;
                const float rsv = rs[m0 + row];
                const float* xp = Ax + (size_t)(m0 + row) * lda + k0 + kc * 8;
                const float* wp = wn + k0 + kc * 8;
                const float4 f0 = *reinterpret_cast<const float4*>(xp);
                const float4 f1 = *reinterpret_cast<const float4*>(xp + 4);
                const float4 w0 = *reinterpret_cast<const float4*>(wp);
                const float4 w1 = *reinterpret_cast<const float4*>(wp + 4);
                uint4 pk;
                pk.x = f2b(f0.x * rsv * w0.x) | ((u32)f2b(f0.y * rsv * w0.y) << 16);
                pk.y = f2b(f0.z * rsv * w0.z) | ((u32)f2b(f0.w * rsv * w0.w) << 16);
                pk.z = f2b(f1.x * rsv * w1.x) | ((u32)f2b(f1.y * rsv * w1.y) << 16);
                pk.w = f2b(f1.z * rsv * w1.z) | ((u32)f2b(f1.w * rsv * w1.w) << 16);
                *reinterpret_cast<uint4*>(&As[row * 64 + (kc ^ (row & 7)) * 8]) = pk;
            }
        } else {
            #pragma unroll
            for (int j2 = 0; j2 < AJ; ++j2) {
                const int R = wave * (BM / 4) + j2 * 8;
                __builtin_amdgcn_global_load_lds(
                    (const u32*)&A[(size_t)(m0 + R + lr) * lda + k0 + skc * 8],
                    (u32*)&As[R * 64], 16, 0, 0);
            }
        }
        #pragma unroll
        for (int j2 = 0; j2 < 4; ++j2) {
            const int R = wave * 32 + j2 * 8;
            __builtin_amdgcn_global_load_lds(
                (const u32*)&Bt[(size_t)(n0 + R + lr) * K + k0 + skc * 8],
                (u32*)&Bs[R * 64], 16, 0, 0);
        }
        __syncthreads();
        #pragma unroll
        for (int ks = 0; ks < 2; ++ks) {
            bf16x8 af[FM], bfr[4];
            const int chunk = ((ks * 4 + (lane >> 4)) ^ (lane & 7)) * 8;
            #pragma unroll
            for (int fm = 0; fm < FM; ++fm) {
                int m = wr * WM + fm * 16 + (lane & 15);
                af[fm] = *reinterpret_cast<const bf16x8*>(&As[m * 64 + chunk]);
            }
            #pragma unroll
            for (int fn = 0; fn < 4; ++fn) {
                int n = wc * 64 + fn * 16 + (lane & 15);
                bfr[fn] = *reinterpret_cast<const bf16x8*>(&Bs[n * 64 + chunk]);
            }
            #pragma unroll
            for (int fm = 0; fm < FM; ++fm)
                #pragma unroll
                for (int fn = 0; fn < 4; ++fn)
                    acc[fm][fn] = __builtin_amdgcn_mfma_f32_16x16x32_bf16(
                        af[fm], bfr[fn], acc[fm][fn], 0, 0, 0);
        }
        __syncthreads();
    }

    #pragma unroll
    for (int fm = 0; fm < FM; ++fm) {
        #pragma unroll
        for (int fn = 0; fn < 4; ++fn) {
            #pragma unroll
            for (int r = 0; r < 4; ++r) {
                int row = m0 + wr * WM + fm * 16 + ((lane >> 4) << 2) + r;
                int col = n0 + wc * 64 + fn * 16 + (lane & 15);
                float v = acc[fm][fn][r];
                size_t ci = (size_t)row * ldc + col;
                if constexpr (EPI == 0) C2[ci] = f2b(v);
                else                    C[ci] += v;
            }
        }
    }
}

// ---------------------------------------------------------------------------
// Generic bf16 MFMA GEMM (padded-LDS path) for the small GEMMs.
// EPI: 2 = softplus(acc+bias) bf16 (C2), 4 = f32 store (C).
// AF32: 1 = A f32 cast during staging.
// ---------------------------------------------------------------------------
template<int BM, int BN, int BK, int EPI, int SPLITK = 1, int AF32 = 0>
__global__ __launch_bounds__(256)
void gemm_k(const u16* __restrict__ A, int lda,
            const u16* __restrict__ Bt, int K,
            float* __restrict__ C, int ldc,
            u16* __restrict__ C2,
            const void* __restrict__ bias, int boff, const int* __restrict__ bff,
            int sstride = 0)
{
    constexpr int PAD = 8;
    constexpr int LDS_S = BK + PAD;
    __shared__ __align__(16) u16 As[BM * LDS_S];
    __shared__ __align__(16) u16 Bs[BN * LDS_S];

    const int tid = threadIdx.x;
    const int m0 = blockIdx.y * BM;
    int n0, kbeg, kend;
    if constexpr (SPLITK > 1) {
        n0 = 0;
        const int ksz = K / SPLITK;
        kbeg = blockIdx.x * ksz;
        kend = kbeg + ksz;
        C += (size_t)blockIdx.x * sstride;
    } else {
        n0 = blockIdx.x * BN;
        kbeg = 0; kend = K;
    }
    const int lane = tid & 63, wv = tid >> 6;
    const int wr = wv >> 1, wc = wv & 1;
    constexpr int WM = BM / 2, WN = BN / 2, FM = WM / 16, FN = WN / 16;
    constexpr int AC = (BM * BK) / 2048;
    constexpr int BC = (BN * BK) / 2048;
    constexpr int KC = BK / 8;

    f32x4 acc[FM][FN] = {};

    for (int k0 = kbeg; k0 < kend; k0 += BK) {
        #pragma unroll
        for (int i = 0; i < AC; ++i) {
            int idx = tid + i * 256;
            int row = idx / KC, kc = idx % KC;
            if constexpr (AF32 == 1) {
                const float* Af = (const float*)A;
                const float4 f0 = *reinterpret_cast<const float4*>(
                    &Af[(size_t)(m0 + row) * lda + k0 + kc * 8]);
                const float4 f1 = *reinterpret_cast<const float4*>(
                    &Af[(size_t)(m0 + row) * lda + k0 + kc * 8 + 4]);
                uint4 pk;
                pk.x = f2b(f0.x) | ((u32)f2b(f0.y) << 16);
                pk.y = f2b(f0.z) | ((u32)f2b(f0.w) << 16);
                pk.z = f2b(f1.x) | ((u32)f2b(f1.y) << 16);
                pk.w = f2b(f1.z) | ((u32)f2b(f1.w) << 16);
                *reinterpret_cast<uint4*>(&As[row * LDS_S + kc * 8]) = pk;
            } else {
                *reinterpret_cast<uint4*>(&As[row * LDS_S + kc * 8]) =
                    *reinterpret_cast<const uint4*>(&A[(size_t)(m0 + row) * lda + k0 + kc * 8]);
            }
        }
        #pragma unroll
        for (int i = 0; i < BC; ++i) {
            int idx = tid + i * 256;
            int row = idx / KC, kc = idx % KC;
            *reinterpret_cast<uint4*>(&Bs[row * LDS_S + kc * 8]) =
                *reinterpret_cast<const uint4*>(&Bt[(size_t)(n0 + row) * K + k0 + kc * 8]);
        }
        __syncthreads();
        #pragma unroll
        for (int ks = 0; ks < BK / 32; ++ks) {
            bf16x8 af[FM], bfr[FN];
            const int koff = ks * 32 + (lane >> 4) * 8;
            #pragma unroll
            for (int fm = 0; fm < FM; ++fm) {
                int m = wr * WM + fm * 16 + (lane & 15);
                af[fm] = *reinterpret_cast<const bf16x8*>(&As[m * LDS_S + koff]);
            }
            #pragma unroll
            for (int fn = 0; fn < FN; ++fn) {
                int n = wc * WN + fn * 16 + (lane & 15);
                bfr[fn] = *reinterpret_cast<const bf16x8*>(&Bs[n * LDS_S + koff]);
            }
            #pragma unroll
            for (int fm = 0; fm < FM; ++fm)
                #pragma unroll
                for (int fn = 0; fn < FN; ++fn)
                    acc[fm][fn] = __builtin_amdgcn_mfma_f32_16x16x32_bf16(
                        af[fm], bfr[fn], acc[fm][fn], 0, 0, 0);
        }
        __syncthreads();
    }

    int bf = 0;
    if constexpr (EPI == 2) bf = bff[0];

    #pragma unroll
    for (int fm = 0; fm < FM; ++fm) {
        #pragma unroll
        for (int fn = 0; fn < FN; ++fn) {
            #pragma unroll
            for (int r = 0; r < 4; ++r) {
                int row = m0 + wr * WM + fm * 16 + ((lane >> 4) << 2) + r;
                int col = n0 + wc * WN + fn * 16 + (lane & 15);
                float v = acc[fm][fn][r];
                size_t ci = (size_t)row * ldc + col;
                if constexpr (EPI == 2) {
                    v += ldf(bias, boff + col, bf);
                    v = (v > 20.f) ? v : __logf(1.f + __expf(v));
                    C2[ci] = f2b(v);
                } else {
                    C[ci] = v;
                }
            }
        }
    }
}

// ---------------------------------------------------------------------------
// Reduce 4 split-K partials: xdf[t] = sum_s xdp[s][t]  (all 64 cols; R13 form)
// ---------------------------------------------------------------------------
__global__ __launch_bounds__(256)
void xred_k(const float* __restrict__ xdp, float* __restrict__ xdf)
{
    const int t = blockIdx.x * 256 + threadIdx.x;
    constexpr int S = 8192 * 64;
    xdf[t] = (xdp[t] + xdp[t + S]) + (xdp[t + 2 * S] + xdp[t + 3 * S]);
}

// ---------------------------------------------------------------------------
// Transpose + cast to bf16: src [K,N] -> dst [N,K] bf16, batched over z
// ---------------------------------------------------------------------------
__global__ __launch_bounds__(256)
void tr_k(const void* __restrict__ src, u16* __restrict__ dst, int K, int N,
          const int* __restrict__ bff)
{
    __shared__ u16 t[32][33];
    const int bf = bff[0];
    const size_t lo = (size_t)blockIdx.z * K * N;
    const int n0 = blockIdx.x * 32, k0 = blockIdx.y * 32;
    const int tx = threadIdx.x & 31, ty = threadIdx.x >> 5;
    #pragma unroll
    for (int q = 0; q < 4; ++q) {
        int r = ty + q * 8;
        size_t si = lo + (size_t)(k0 + r) * N + n0 + tx;
        t[r][tx] = bf ? ((const u16*)src)[si] : f2b(((const float*)src)[si]);
    }
    __syncthreads();
    #pragma unroll
    for (int q = 0; q < 4; ++q) {
        int r = ty + q * 8;
        dst[lo + (size_t)(n0 + r) * K + k0 + tx] = t[tx][r];
    }
}

// ---------------------------------------------------------------------------
// Scatter visible tokens + pos_embed. x f32 [8,1024,512]
// ---------------------------------------------------------------------------
__global__ __launch_bounds__(128)
void embed_k(const void* __restrict__ xv, const int* __restrict__ ids,
             const void* __restrict__ mtok, const void* __restrict__ pos,
             float* __restrict__ x, const int* __restrict__ bff)
{
    const int bf = bff[0];
    const int bid = blockIdx.x;
    const int p = bid & 1023, b = bid >> 10;
    const int* row = ids + b * 256;
    int lo = 0, hi = 256;
    while (lo < hi) { int mid = (lo + hi) >> 1; if (row[mid] <= p) lo = mid + 1; else hi = mid; }
    const int j = (lo > 0 && row[lo - 1] == p) ? (lo - 1) : -1;
    const int c = threadIdx.x * 4;
    const size_t sbase = (j >= 0) ? ((size_t)(b * 256 + j) * 512 + c) : (size_t)c;
    const void* srcp = (j >= 0) ? xv : mtok;
    const size_t o = (size_t)(b * 1024 + p) * 512 + c;
    #pragma unroll
    for (int e = 0; e < 4; ++e)
        x[o + e] = ldf(srcp, sbase + e, bf) + ldf(pos, (size_t)p * 512 + c + e, bf);
}

// ---------------------------------------------------------------------------
// Causal depthwise conv (D_CONV=4) + bias + silu. bf16 in/out, f32 accum.
// ---------------------------------------------------------------------------
__global__ __launch_bounds__(256)
void conv_k(const u16* __restrict__ uz, const void* __restrict__ cw, int cwo,
            const void* __restrict__ cb, int cbo,
            u16* __restrict__ ucb, const int* __restrict__ bff)
{
    const int bf = bff[0];
    const int bid = blockIdx.x, tid = threadIdx.x;
    const int d = (bid & 3) * 256 + tid;
    const int lg = (bid >> 2) & 127;
    const int b = bid >> 9;
    const int l0 = lg * 8;
    const float w0 = ldf(cw, cwo + d * 4 + 0, bf), w1 = ldf(cw, cwo + d * 4 + 1, bf);
    const float w2 = ldf(cw, cwo + d * 4 + 2, bf), w3 = ldf(cw, cwo + d * 4 + 3, bf);
    const float bias = ldf(cb, cbo + d, bf);
    float u[11];
    #pragma unroll
    for (int j = 0; j < 11; ++j) {
        int l = l0 - 3 + j;
        u[j] = (l >= 0) ? b2f(uz[(size_t)(b * 1024 + l) * 2048 + d]) : 0.f;
    }
    #pragma unroll
    for (int i = 0; i < 8; ++i) {
        float a = bias + w0 * u[i] + w1 * u[i + 1] + w2 * u[i + 2] + w3 * u[i + 3];
        float s = a * (1.f / (1.f + __expf(-a)));
        ucb[(size_t)(b * 1024 + l0 + i) * 1024 + d] = f2b(s);
    }
}

// ===========================================================================
// Chunked selective scan (64 chunks x 16), 3 kernels (proven R13 structure):
//  scan1: local scan from h=0, y_loc = C.h_loc + u*D (bf16) + carry.
//  carry: in-place chunk-carry propagation (bf16 states).
//  scan2: correction: y = (y_loc + sum_s P_l[s]*h_in[s]*C_l[s]) * silu(z).
// Structured-A: P_l[s] = q_l^(s+1), one exp + power chains.
// ===========================================================================
__global__ __launch_bounds__(256)
void scan1_k(const u16* __restrict__ uz, const u16* __restrict__ ucb,
             const float* __restrict__ xdbl, const float* __restrict__ a2f, int alo,
             const float* __restrict__ df, int dso,
             u16* __restrict__ hcar, float* __restrict__ dtsum,
             u16* __restrict__ yloc, const int* __restrict__ astrp)
{
    const int tid = threadIdx.x;
    const int d = (blockIdx.x << 8) + tid;
    const int c = blockIdx.y, b = blockIdx.z;
    const int l0 = c * 16;
    const int astr = astrp[0];
    float h[16];
    #pragma unroll
    for (int s = 0; s < 16; ++s) h[s] = 0.f;
    const float* ap = &a2f[alo + d * 16];
    float A2[16];
    const float A2_0 = ap[0];
    if (!astr) {
        #pragma unroll
        for (int s = 0; s < 16; s += 4) {
            const float4 av = *reinterpret_cast<const float4*>(&ap[s]);
            A2[s] = av.x; A2[s+1] = av.y; A2[s+2] = av.z; A2[s+3] = av.w;
        }
    }
    const float Dv = df[dso + d];
    float dsum = 0.f;
    const u16* uzp = uz  + (size_t)(b * 1024 + l0) * 2048 + d;
    const u16* ucp = ucb + (size_t)(b * 1024 + l0) * 1024 + d;
    const float* xb = xdbl + (size_t)(b * 1024 + l0) * 64 + 32;
    u16* ylp = yloc + (size_t)(b * 1024 + l0) * 1024 + d;
    if (astr) {
        #pragma unroll 8
        for (int i = 0; i < 16; ++i) {
            float dtv = b2f(uzp[(size_t)i * 2048]);
            float uv  = b2f(ucp[(size_t)i * 1024]);
            float dtu = dtv * uv;
            dsum += dtv;
            const float4 B0 = *reinterpret_cast<const float4*>(xb + i * 64);
            const float4 B1 = *reinterpret_cast<const float4*>(xb + i * 64 + 4);
            const float4 B2 = *reinterpret_cast<const float4*>(xb + i * 64 + 8);
            const float4 B3 = *reinterpret_cast<const float4*>(xb + i * 64 + 12);
            const float4 C0 = *reinterpret_cast<const float4*>(xb + i * 64 + 16);
            const float4 C1 = *reinterpret_cast<const float4*>(xb + i * 64 + 20);
            const float4 C2 = *reinterpret_cast<const float4*>(xb + i * 64 + 24);
            const float4 C3 = *reinterpret_cast<const float4*>(xb + i * 64 + 28);
            const float Bv[16] = {B0.x,B0.y,B0.z,B0.w, B1.x,B1.y,B1.z,B1.w,
                                  B2.x,B2.y,B2.z,B2.w, B3.x,B3.y,B3.z,B3.w};
            const float Cv[16] = {C0.x,C0.y,C0.z,C0.w, C1.x,C1.y,C1.z,C1.w,
                                  C2.x,C2.y,C2.z,C2.w, C3.x,C3.y,C3.z,C3.w};
            float q  = exp2f(dtv * A2_0);
            float q2 = q * q, q3 = q2 * q, q4 = q2 * q2;
            float g1 = q, g2 = q2, g3 = q3, g4 = q4;
            float yv = 0.f;
            #pragma unroll
            for (int gr = 0; gr < 4; ++gr) {
                h[4*gr+0] = g1 * h[4*gr+0] + dtu * Bv[4*gr+0];
                h[4*gr+1] = g2 * h[4*gr+1] + dtu * Bv[4*gr+1];
                h[4*gr+2] = g3 * h[4*gr+2] + dtu * Bv[4*gr+2];
                h[4*gr+3] = g4 * h[4*gr+3] + dtu * Bv[4*gr+3];
                yv += h[4*gr+0] * Cv[4*gr+0] + h[4*gr+1] * Cv[4*gr+1]
                    + h[4*gr+2] * Cv[4*gr+2] + h[4*gr+3] * Cv[4*gr+3];
                if (gr < 3) { g1 *= q4; g2 *= q4; g3 *= q4; g4 *= q4; }
            }
            ylp[(size_t)i * 1024] = f2b(yv + uv * Dv);
        }
    } else {
        #pragma unroll 4
        for (int i = 0; i < 16; ++i) {
            float dtv = b2f(uzp[(size_t)i * 2048]);
            float uv  = b2f(ucp[(size_t)i * 1024]);
            float dtu = dtv * uv;
            dsum += dtv;
            const float4 B0 = *reinterpret_cast<const float4*>(xb + i * 64);
            const float4 B1 = *reinterpret_cast<const float4*>(xb + i * 64 + 4);
            const float4 B2 = *reinterpret_cast<const float4*>(xb + i * 64 + 8);
            const float4 B3 = *reinterpret_cast<const float4*>(xb + i * 64 + 12);
            const float4 C0 = *reinterpret_cast<const float4*>(xb + i * 64 + 16);
            const float4 C1 = *reinterpret_cast<const float4*>(xb + i * 64 + 20);
            const float4 C2 = *reinterpret_cast<const float4*>(xb + i * 64 + 24);
            const float4 C3 = *reinterpret_cast<const float4*>(xb + i * 64 + 28);
            const float Bv[16] = {B0.x,B0.y,B0.z,B0.w, B1.x,B1.y,B1.z,B1.w,
                                  B2.x,B2.y,B2.z,B2.w, B3.x,B3.y,B3.z,B3.w};
            const float Cv[16] = {C0.x,C0.y,C0.z,C0.w, C1.x,C1.y,C1.z,C1.w,
                                  C2.x,C2.y,C2.z,C2.w, C3.x,C3.y,C3.z,C3.w};
            float yv = 0.f;
            #pragma unroll
            for (int s = 0; s < 16; ++s) {
                h[s] = exp2f(dtv * A2[s]) * h[s] + dtu * Bv[s];
                yv += h[s] * Cv[s];
            }
            ylp[(size_t)i * 1024] = f2b(yv + uv * Dv);
        }
    }
    u16* hp = &hcar[((size_t)(b * 64 + c) * 1024 + d) * 16];
    #pragma unroll
    for (int s = 0; s < 16; s += 8) {
        uint4 pk;
        pk.x = f2b(h[s+0]) | ((u32)f2b(h[s+1]) << 16);
        pk.y = f2b(h[s+2]) | ((u32)f2b(h[s+3]) << 16);
        pk.z = f2b(h[s+4]) | ((u32)f2b(h[s+5]) << 16);
        pk.w = f2b(h[s+6]) | ((u32)f2b(h[s+7]) << 16);
        *reinterpret_cast<uint4*>(&hp[s]) = pk;
    }
    dtsum[(size_t)(b * 64 + c) * 1024 + d] = dsum;
}

__global__ __launch_bounds__(256)
void carry_k(u16* __restrict__ hcar, const float* __restrict__ dtsum,
             const float* __restrict__ a2f, int alo)
{
    const int t = blockIdx.x * 256 + threadIdx.x;   // (b, d, s)
    const int b = t >> 14;
    const int ds = t & 16383;
    const int d = ds >> 4;
    const float A2 = a2f[alo + ds];
    float h = 0.f;
    #pragma unroll 8
    for (int c = 0; c < 64; ++c) {
        const size_t idx = (size_t)(b * 64 + c) * 16384 + ds;
        const float hl = b2f(hcar[idx]);
        hcar[idx] = f2b(h);                          // entry state for scan2
        h = exp2f(A2 * dtsum[(size_t)(b * 64 + c) * 1024 + d]) * h + hl;
    }
}

__global__ __launch_bounds__(256)
void scan2_k(const u16* __restrict__ uz, const u16* __restrict__ yloc,
             const float* __restrict__ xdbl, const float* __restrict__ a2f, int alo,
             const u16* __restrict__ hcar, u16* __restrict__ y,
             const int* __restrict__ astrp)
{
    const int tid = threadIdx.x;
    const int d = (blockIdx.x << 8) + tid;
    const int c = blockIdx.y, b = blockIdx.z;
    const int l0 = c * 16;
    const int astr = astrp[0];
    float hs[16];
    const float* ap = &a2f[alo + d * 16];
    const u16* hp = &hcar[(size_t)(b * 64 + c) * 16384 + d * 16];
    const float A2_0 = ap[0];
    float A2[16];
    if (!astr) {
        #pragma unroll
        for (int s = 0; s < 16; s += 4) {
            const float4 av = *reinterpret_cast<const float4*>(&ap[s]);
            A2[s] = av.x; A2[s+1] = av.y; A2[s+2] = av.z; A2[s+3] = av.w;
        }
    }
    #pragma unroll
    for (int s = 0; s < 16; s += 8) {
        const uint4 pk = *reinterpret_cast<const uint4*>(&hp[s]);
        hs[s+0] = b2f((u16)(pk.x & 0xffff)); hs[s+1] = b2f((u16)(pk.x >> 16));
        hs[s+2] = b2f((u16)(pk.y & 0xffff)); hs[s+3] = b2f((u16)(pk.y >> 16));
        hs[s+4] = b2f((u16)(pk.z & 0xffff)); hs[s+5] = b2f((u16)(pk.z >> 16));
        hs[s+6] = b2f((u16)(pk.w & 0xffff)); hs[s+7] = b2f((u16)(pk.w >> 16));
    }
    const u16* uzp = uz   + (size_t)(b * 1024 + l0) * 2048 + d;
    const u16* ylp = yloc + (size_t)(b * 1024 + l0) * 1024 + d;
    const float* xb = xdbl + (size_t)(b * 1024 + l0) * 64 + 48;  // C cols only
    u16* yp_ = y + (size_t)(b * 1024 + l0) * 1024 + d;
    float S = 0.f;
    if (astr) {
        #pragma unroll 8
        for (int i = 0; i < 16; ++i) {
            float dtv = b2f(uzp[(size_t)i * 2048]);
            float zv  = b2f(uzp[(size_t)i * 2048 + 1024]);
            float ylv = b2f(ylp[(size_t)i * 1024]);
            S += dtv;
            const float4 C0 = *reinterpret_cast<const float4*>(xb + i * 64);
            const float4 C1 = *reinterpret_cast<const float4*>(xb + i * 64 + 4);
            const float4 C2 = *reinterpret_cast<const float4*>(xb + i * 64 + 8);
            const float4 C3 = *reinterpret_cast<const float4*>(xb + i * 64 + 12);
            const float Cv[16] = {C0.x,C0.y,C0.z,C0.w, C1.x,C1.y,C1.z,C1.w,
                                  C2.x,C2.y,C2.z,C2.w, C3.x,C3.y,C3.z,C3.w};
            float q  = exp2f(S * A2_0);
            float q2 = q * q, q3 = q2 * q, q4 = q2 * q2;
            float g1 = q, g2 = q2, g3 = q3, g4 = q4;
            float corr = 0.f;
            #pragma unroll
            for (int gr = 0; gr < 4; ++gr) {
                corr += (g1 * hs[4*gr+0]) * Cv[4*gr+0] + (g2 * hs[4*gr+1]) * Cv[4*gr+1]
                      + (g3 * hs[4*gr+2]) * Cv[4*gr+2] + (g4 * hs[4*gr+3]) * Cv[4*gr+3];
                if (gr < 3) { g1 *= q4; g2 *= q4; g3 *= q4; g4 *= q4; }
            }
            float yo = (ylv + corr) * (zv * (1.f / (1.f + __expf(-zv))));
            yp_[(size_t)i * 1024] = f2b(yo);
        }
    } else {
        #pragma unroll 4
        for (int i = 0; i < 16; ++i) {
            float dtv = b2f(uzp[(size_t)i * 2048]);
            float zv  = b2f(uzp[(size_t)i * 2048 + 1024]);
            float ylv = b2f(ylp[(size_t)i * 1024]);
            S += dtv;
            const float4 C0 = *reinterpret_cast<const float4*>(xb + i * 64);
            const float4 C1 = *reinterpret_cast<const float4*>(xb + i * 64 + 4);
            const float4 C2 = *reinterpret_cast<const float4*>(xb + i * 64 + 8);
            const float4 C3 = *reinterpret_cast<const float4*>(xb + i * 64 + 12);
            const float Cv[16] = {C0.x,C0.y,C0.z,C0.w, C1.x,C1.y,C1.z,C1.w,
                                  C2.x,C2.y,C2.z,C2.w, C3.x,C3.y,C3.z,C3.w};
            float corr = 0.f;
            #pragma unroll
            for (int s = 0; s < 16; ++s)
                corr += (exp2f(S * A2[s]) * hs[s]) * Cv[s];
            float yo = (ylv + corr) * (zv * (1.f / (1.f + __expf(-zv))));
            yp_[(size_t)i * 1024] = f2b(yo);
        }
    }
}

// ---------------------------------------------------------------------------
// Final RMSNorm + head GEMV (512 -> 16) + bias
// ---------------------------------------------------------------------------
__global__ __launch_bounds__(128)
void head_k(const float* __restrict__ x, const void* __restrict__ nw,
            const void* __restrict__ hw, const void* __restrict__ hb,
            void* __restrict__ out, const int* __restrict__ bff)
{
    const int bf = bff[0];
    const int row = blockIdx.x, tid = threadIdx.x;
    __shared__ float xs[512];
    __shared__ float pr[128];
    __shared__ float sred[2];
    const float4 v = *reinterpret_cast<const float4*>(&x[(size_t)row * 512 + tid * 4]);
    float ss = v.x * v.x + v.y * v.y + v.z * v.z + v.w * v.w;
    #pragma unroll
    for (int off = 32; off >= 1; off >>= 1) ss += __shfl_xor(ss, off);
    if ((tid & 63) == 0) sred[tid >> 6] = ss;
    __syncthreads();
    const float scale = rsqrtf((sred[0] + sred[1]) * (1.f / 512.f) + 1e-6f);
    const int c = tid * 4;
    xs[c + 0] = v.x * scale * ldf(nw, c + 0, bf);
    xs[c + 1] = v.y * scale * ldf(nw, c + 1, bf);
    xs[c + 2] = v.z * scale * ldf(nw, c + 2, bf);
    xs[c + 3] = v.w * scale * ldf(nw, c + 3, bf);
    __syncthreads();
    const int n = tid & 15, kg = tid >> 4;
    float s = 0.f;
    if (bf) {
        #pragma unroll 8
        for (int k = kg * 64; k < kg * 64 + 64; ++k)
            s += xs[k] * b2f(((const u16*)hw)[k * 16 + n]);
    } else {
        #pragma unroll 8
        for (int k = kg * 64; k < kg * 64 + 64; ++k)
            s += xs[k] * ((const float*)hw)[k * 16 + n];
    }
    pr[tid] = s;
    __syncthreads();
    if (tid < 16) {
        float a = ldf(hb, tid, bf);
        #pragma unroll
        for (int g = 0; g < 8; ++g) a += pr[g * 16 + tid];
        if (bf) ((u16*)out)[(size_t)row * 16 + tid] = f2b(a);
        else    ((float*)out)[(size_t)row * 16 + tid] = a;
    }
}

// ---------------------------------------------------------------------------
extern "C" void kernel_launch(void* const* d_in, const int* in_sizes, int n_in,
                              void* d_out, int out_size, void* d_ws, size_t ws_size,
                              hipStream_t stream)
{
    const void* xv   = d_in[0];
    const int*  ids  = (const int*)d_in[1];
    const void* mtok = d_in[2];
    const void* pos  = d_in[3];
    const void* inw  = d_in[4];
    const void* cw   = d_in[5];
    const void* cb   = d_in[6];
    const void* xpw  = d_in[7];
    const void* dtw  = d_in[8];
    const void* dtb  = d_in[9];
    const void* alog = d_in[10];
    const void* dsk  = d_in[11];
    const void* outw = d_in[12];
    const void* bnw  = d_in[13];
    const void* nw   = d_in[14];
    const void* hw   = d_in[15];
    const void* hb   = d_in[16];
    (void)in_sizes; (void)n_in; (void)out_size; (void)ws_size;

    char* base = (char*)d_ws;
    size_t off = 0;
    auto alloc = [&](size_t bytes) {
        char* p = base + off;
        off += (bytes + 255) & ~(size_t)255;
        return p;
    };
    int*   flag = (int*)  alloc(256);                  // [0]=dtype, [1]=A-structured
    float* x    = (float*)alloc(8192ull * 512 * 4);    // residual stream
    float* rsb  = (float*)alloc(8192ull * 4);          // per-row rms scales
    u16*   uzb  = (u16*)  alloc(8192ull * 2048 * 2);   // [u|z] bf16; u-half reused for dt
    u16*   ucb  = (u16*)  alloc(8192ull * 1024 * 2);   // conv+silu out bf16
    float* xdf  = (float*)alloc(8192ull * 64 * 4);     // x_dbl f32 (reduced)
    float* xdp  = (float*)alloc(4ull * 8192 * 64 * 4); // x_dbl split-K partials
    u16*   yb   = (u16*)  alloc(8192ull * 1024 * 2);   // gated y bf16
    u16*   ylb  = (u16*)  alloc(8192ull * 1024 * 2);   // local y (pre-gate) bf16
    u16*   wTin = (u16*)  alloc(4ull * 2048 * 512 * 2);
    u16*   wTxp = (u16*)  alloc(4ull * 64 * 1024 * 2);
    u16*   wTdt = (u16*)  alloc(4ull * 1024 * 32 * 2);
    u16*   wTout= (u16*)  alloc(4ull * 512 * 1024 * 2);
    float* dtsum= (float*)alloc(8ull * 64 * 1024 * 4);   // chunk carries: sum(dt)
    u16*   hcar = (u16*)  alloc(8ull * 64 * 16384 * 2);  // local sums -> entry states (bf16)
    float* a2f  = (float*)alloc(4ull * 16384 * 4);       // -exp(A_log)*log2e
    float* dff  = (float*)alloc(4ull * 1024 * 4);        // D_skip f32
    float* bnwf = (float*)alloc(4ull * 512 * 4);         // block_norm_w f32

    prep_k<<<256, 256, 0, stream>>>(alog, dsk, nw, bnw, a2f, dff, bnwf, flag);

    // Transpose all layer weights to bf16 [N,K] once
    tr_k<<<dim3(2048 / 32, 512 / 32, 4), 256, 0, stream>>>(inw, wTin, 512, 2048, flag);
    tr_k<<<dim3(64 / 32, 1024 / 32, 4), 256, 0, stream>>>(xpw, wTxp, 1024, 64, flag);
    tr_k<<<dim3(1024 / 32, 32 / 32, 4), 256, 0, stream>>>(dtw, wTdt, 32, 1024, flag);
    tr_k<<<dim3(512 / 32, 1024 / 32, 4), 256, 0, stream>>>(outw, wTout, 1024, 512, flag);

    embed_k<<<8192, 128, 0, stream>>>(xv, ids, mtok, pos, x, flag);

    for (int i = 0; i < 4; ++i) {
        // per-row rms scales (replaces full rms_k; norm fused into in_proj)
        rscale_k<<<2048, 256, 0, stream>>>(x, rsb);
        // in_proj: rmsnorm(x) @ [512,2048] -> uz bf16 (fused staging, gld B)
        gemm_gld_k<128, 0, 1><<<dim3(16, 64), 256, 0, stream>>>(
            nullptr, 512, wTin + (size_t)i * 2048 * 512, 512, nullptr, 2048, uzb,
            x, rsb, bnwf + i * 512);
        conv_k<<<4096, 256, 0, stream>>>(uzb, cw, i * 4096, cb, i * 1024, ucb, flag);
        // x_proj: [8192,1024] @ [1024,64], split-K=4 -> partials, then reduce
        gemm_k<64, 64, 64, 4, 4><<<dim3(4, 128), 256, 0, stream>>>(
            ucb, 1024, wTxp + (size_t)i * 64 * 1024, 1024, xdp, 64, nullptr,
            nullptr, 0, nullptr, 8192 * 64);
        xred_k<<<2048, 256, 0, stream>>>(xdp, xdf);
        // dt_proj: [8192,32] @ [32,1024] + bias -> fast softplus -> dt bf16
        gemm_k<64, 64, 32, 2, 1, 1><<<dim3(16, 128), 256, 0, stream>>>(
            (const u16*)xdf, 64, wTdt + (size_t)i * 1024 * 32, 32, nullptr, 2048, uzb,
            dtb, i * 1024, flag);
        // chunked scan: local scan + y_loc, carry, light correction (3 kernels)
        scan1_k<<<dim3(4, 64, 8), 256, 0, stream>>>(
            uzb, ucb, xdf, a2f, i * 16384, dff, i * 1024, hcar, dtsum, ylb, flag + 1);
        carry_k<<<512, 256, 0, stream>>>(hcar, dtsum, a2f, i * 16384);
        scan2_k<<<dim3(4, 64, 8), 256, 0, stream>>>(
            uzb, ylb, xdf, a2f, i * 16384, hcar, yb, flag + 1);
        // out_proj: [8192,1024] @ [1024,512] += residual x (gld path, XCD-swizzled)
        gemm_gld_k<64, 1><<<dim3(4, 128), 256, 0, stream>>>(
            yb, 1024, wTout + (size_t)i * 512 * 1024, 1024, x, 512, nullptr);
    }

    head_k<<<8192, 128, 0, stream>>>(x, nw, hw, hb, d_out, flag);
}

// Round 17
// 766.897 us; speedup vs baseline: 1.0388x; 1.0388x over previous
//
#include <hip/hip_runtime.h>

typedef unsigned short u16;
typedef unsigned int   u32;
typedef __attribute__((ext_vector_type(8))) short bf16x8;
typedef __attribute__((ext_vector_type(4))) float f32x4;

__device__ __forceinline__ float b2f(u16 u) {
    union { u32 i; float f; } v; v.i = ((u32)u) << 16; return v.f;
}
__device__ __forceinline__ u16 f2b(float f) {
    union { float f; u32 i; } v; v.f = f;
    u32 x = v.i;
    return (u16)((x + 0x7fffu + ((x >> 16) & 1u)) >> 16);
}
// dtype-agnostic parameter read: bf=1 -> bf16 source, bf=0 -> f32 source
__device__ __forceinline__ float ldf(const void* p, size_t i, int bf) {
    return bf ? b2f(((const u16*)p)[i]) : ((const float*)p)[i];
}

// ---------------------------------------------------------------------------
// Precompute per-layer scan constants; detect dtype; verify A structure.
// flag[0]=dtype (bf16?), flag[1]=A-structured (cleared on mismatch).
// ---------------------------------------------------------------------------
__global__ __launch_bounds__(256)
void prep_k(const void* __restrict__ alog, const void* __restrict__ dsk,
            const void* __restrict__ normw,
            float* __restrict__ a2f, float* __restrict__ df,
            int* __restrict__ flag)
{
    const int bf = (((const u16*)normw)[0] == 0x3F80u) ? 1 : 0;
    const int t = blockIdx.x * 256 + threadIdx.x;
    if (t == 0) { flag[0] = bf; flag[1] = 1; }
    const float v = -expf(ldf(alog, t, bf)) * 1.44269504f;
    a2f[t] = v;
    const float base = -expf(ldf(alog, t & ~15, bf)) * 1.44269504f;
    const float expect = (float)((t & 15) + 1) * base;
    if (fabsf(v - expect) > 1e-4f * fabsf(expect) + 1e-7f)
        atomicAnd(&flag[1], 0);
    if (t < 4096) df[t] = ldf(dsk, t, bf);
}

// ===========================================================================
// BMx128x64 bf16 MFMA GEMM with global_load_lds (width=16) staging,
// XOR-swizzled LDS layout, XCD-aware block remap.
// EPI: 0 = bf16 store (C2), 1 = f32 += (C)
// ===========================================================================
template<int BM, int EPI>
__global__ __launch_bounds__(256)
void gemm_gld_k(const u16* __restrict__ A, int lda,
                const u16* __restrict__ Bt, int K,
                float* __restrict__ C, int ldc,
                u16* __restrict__ C2)
{
    __shared__ __align__(16) u16 As[BM * 64];
    __shared__ __align__(16) u16 Bs[128 * 64];

    const int tid = threadIdx.x;
    const int NX = gridDim.x, NY = gridDim.y;
    const int bid = blockIdx.y * NX + blockIdx.x;
    const int xcd = bid & 7, j = bid >> 3;
    const int m_idx = xcd * (NY >> 3) + j / NX;
    const int n_idx = j % NX;
    const int m0 = m_idx * BM, n0 = n_idx * 128;

    const int lane = tid & 63, wave = tid >> 6;
    const int wr = wave >> 1, wc = wave & 1;
    constexpr int WM = BM / 2, FM = WM / 16;
    constexpr int AJ = BM / 32;

    const int lr = lane >> 3;
    const int skc = (lane & 7) ^ lr;

    f32x4 acc[FM][4] = {};

    for (int k0 = 0; k0 < K; k0 += 64) {
        #pragma unroll
        for (int j2 = 0; j2 < AJ; ++j2) {
            const int R = wave * (BM / 4) + j2 * 8;
            __builtin_amdgcn_global_load_lds(
                (const u32*)&A[(size_t)(m0 + R + lr) * lda + k0 + skc * 8],
                (u32*)&As[R * 64], 16, 0, 0);
        }
        #pragma unroll
        for (int j2 = 0; j2 < 4; ++j2) {
            const int R = wave * 32 + j2 * 8;
            __builtin_amdgcn_global_load_lds(
                (const u32*)&Bt[(size_t)(n0 + R + lr) * K + k0 + skc * 8],
                (u32*)&Bs[R * 64], 16, 0, 0);
        }
        __syncthreads();
        #pragma unroll
        for (int ks = 0; ks < 2; ++ks) {
            bf16x8 af[FM], bfr[4];
            const int chunk = ((ks * 4 + (lane >> 4)) ^ (lane & 7)) * 8;
            #pragma unroll
            for (int fm = 0; fm < FM; ++fm) {
                int m = wr * WM + fm * 16 + (lane & 15);
                af[fm] = *reinterpret_cast<const bf16x8*>(&As[m * 64 + chunk]);
            }
            #pragma unroll
            for (int fn = 0; fn < 4; ++fn) {
                int n = wc * 64 + fn * 16 + (lane & 15);
                bfr[fn] = *reinterpret_cast<const bf16x8*>(&Bs[n * 64 + chunk]);
            }
            #pragma unroll
            for (int fm = 0; fm < FM; ++fm)
                #pragma unroll
                for (int fn = 0; fn < 4; ++fn)
                    acc[fm][fn] = __builtin_amdgcn_mfma_f32_16x16x32_bf16(
                        af[fm], bfr[fn], acc[fm][fn], 0, 0, 0);
        }
        __syncthreads();
    }

    #pragma unroll
    for (int fm = 0; fm < FM; ++fm) {
        #pragma unroll
        for (int fn = 0; fn < 4; ++fn) {
            #pragma unroll
            for (int r = 0; r < 4; ++r) {
                int row = m0 + wr * WM + fm * 16 + ((lane >> 4) << 2) + r;
                int col = n0 + wc * 64 + fn * 16 + (lane & 15);
                float v = acc[fm][fn][r];
                size_t ci = (size_t)row * ldc + col;
                if constexpr (EPI == 0) C2[ci] = f2b(v);
                else                    C[ci] += v;
            }
        }
    }
}

// ---------------------------------------------------------------------------
// Generic bf16 MFMA GEMM (padded-LDS path) for the small GEMMs.
// EPI: 2 = softplus(acc+bias) bf16 (C2), 4 = f32 store (C).
// AF32: 1 = A f32 cast during staging.
// ---------------------------------------------------------------------------
template<int BM, int BN, int BK, int EPI, int SPLITK = 1, int AF32 = 0>
__global__ __launch_bounds__(256)
void gemm_k(const u16* __restrict__ A, int lda,
            const u16* __restrict__ Bt, int K,
            float* __restrict__ C, int ldc,
            u16* __restrict__ C2,
            const void* __restrict__ bias, int boff, const int* __restrict__ bff,
            int sstride = 0)
{
    constexpr int PAD = 8;
    constexpr int LDS_S = BK + PAD;
    __shared__ __align__(16) u16 As[BM * LDS_S];
    __shared__ __align__(16) u16 Bs[BN * LDS_S];

    const int tid = threadIdx.x;
    const int m0 = blockIdx.y * BM;
    int n0, kbeg, kend;
    if constexpr (SPLITK > 1) {
        n0 = 0;
        const int ksz = K / SPLITK;
        kbeg = blockIdx.x * ksz;
        kend = kbeg + ksz;
        C += (size_t)blockIdx.x * sstride;
    } else {
        n0 = blockIdx.x * BN;
        kbeg = 0; kend = K;
    }
    const int lane = tid & 63, wv = tid >> 6;
    const int wr = wv >> 1, wc = wv & 1;
    constexpr int WM = BM / 2, WN = BN / 2, FM = WM / 16, FN = WN / 16;
    constexpr int AC = (BM * BK) / 2048;
    constexpr int BC = (BN * BK) / 2048;
    constexpr int KC = BK / 8;

    f32x4 acc[FM][FN] = {};

    for (int k0 = kbeg; k0 < kend; k0 += BK) {
        #pragma unroll
        for (int i = 0; i < AC; ++i) {
            int idx = tid + i * 256;
            int row = idx / KC, kc = idx % KC;
            if constexpr (AF32 == 1) {
                const float* Af = (const float*)A;
                const float4 f0 = *reinterpret_cast<const float4*>(
                    &Af[(size_t)(m0 + row) * lda + k0 + kc * 8]);
                const float4 f1 = *reinterpret_cast<const float4*>(
                    &Af[(size_t)(m0 + row) * lda + k0 + kc * 8 + 4]);
                uint4 pk;
                pk.x = f2b(f0.x) | ((u32)f2b(f0.y) << 16);
                pk.y = f2b(f0.z) | ((u32)f2b(f0.w) << 16);
                pk.z = f2b(f1.x) | ((u32)f2b(f1.y) << 16);
                pk.w = f2b(f1.z) | ((u32)f2b(f1.w) << 16);
                *reinterpret_cast<uint4*>(&As[row * LDS_S + kc * 8]) = pk;
            } else {
                *reinterpret_cast<uint4*>(&As[row * LDS_S + kc * 8]) =
                    *reinterpret_cast<const uint4*>(&A[(size_t)(m0 + row) * lda + k0 + kc * 8]);
            }
        }
        #pragma unroll
        for (int i = 0; i < BC; ++i) {
            int idx = tid + i * 256;
            int row = idx / KC, kc = idx % KC;
            *reinterpret_cast<uint4*>(&Bs[row * LDS_S + kc * 8]) =
                *reinterpret_cast<const uint4*>(&Bt[(size_t)(n0 + row) * K + k0 + kc * 8]);
        }
        __syncthreads();
        #pragma unroll
        for (int ks = 0; ks < BK / 32; ++ks) {
            bf16x8 af[FM], bfr[FN];
            const int koff = ks * 32 + (lane >> 4) * 8;
            #pragma unroll
            for (int fm = 0; fm < FM; ++fm) {
                int m = wr * WM + fm * 16 + (lane & 15);
                af[fm] = *reinterpret_cast<const bf16x8*>(&As[m * LDS_S + koff]);
            }
            #pragma unroll
            for (int fn = 0; fn < FN; ++fn) {
                int n = wc * WN + fn * 16 + (lane & 15);
                bfr[fn] = *reinterpret_cast<const bf16x8*>(&Bs[n * LDS_S + koff]);
            }
            #pragma unroll
            for (int fm = 0; fm < FM; ++fm)
                #pragma unroll
                for (int fn = 0; fn < FN; ++fn)
                    acc[fm][fn] = __builtin_amdgcn_mfma_f32_16x16x32_bf16(
                        af[fm], bfr[fn], acc[fm][fn], 0, 0, 0);
        }
        __syncthreads();
    }

    int bf = 0;
    if constexpr (EPI == 2) bf = bff[0];

    #pragma unroll
    for (int fm = 0; fm < FM; ++fm) {
        #pragma unroll
        for (int fn = 0; fn < FN; ++fn) {
            #pragma unroll
            for (int r = 0; r < 4; ++r) {
                int row = m0 + wr * WM + fm * 16 + ((lane >> 4) << 2) + r;
                int col = n0 + wc * WN + fn * 16 + (lane & 15);
                float v = acc[fm][fn][r];
                size_t ci = (size_t)row * ldc + col;
                if constexpr (EPI == 2) {
                    v += ldf(bias, boff + col, bf);
                    v = (v > 20.f) ? v : __logf(1.f + __expf(v));
                    C2[ci] = f2b(v);
                } else {
                    C[ci] = v;
                }
            }
        }
    }
}

// ---------------------------------------------------------------------------
// Reduce 4 split-K partials: xdf[t] = sum_s xdp[s][t]
// ---------------------------------------------------------------------------
__global__ __launch_bounds__(256)
void xred_k(const float* __restrict__ xdp, float* __restrict__ xdf)
{
    const int t = blockIdx.x * 256 + threadIdx.x;
    constexpr int S = 8192 * 64;
    xdf[t] = (xdp[t] + xdp[t + S]) + (xdp[t + 2 * S] + xdp[t + 3 * S]);
}

// ---------------------------------------------------------------------------
// Transpose + cast to bf16: src [K,N] -> dst [N,K] bf16, batched over z
// ---------------------------------------------------------------------------
__global__ __launch_bounds__(256)
void tr_k(const void* __restrict__ src, u16* __restrict__ dst, int K, int N,
          const int* __restrict__ bff)
{
    __shared__ u16 t[32][33];
    const int bf = bff[0];
    const size_t lo = (size_t)blockIdx.z * K * N;
    const int n0 = blockIdx.x * 32, k0 = blockIdx.y * 32;
    const int tx = threadIdx.x & 31, ty = threadIdx.x >> 5;
    #pragma unroll
    for (int q = 0; q < 4; ++q) {
        int r = ty + q * 8;
        size_t si = lo + (size_t)(k0 + r) * N + n0 + tx;
        t[r][tx] = bf ? ((const u16*)src)[si] : f2b(((const float*)src)[si]);
    }
    __syncthreads();
    #pragma unroll
    for (int q = 0; q < 4; ++q) {
        int r = ty + q * 8;
        dst[lo + (size_t)(n0 + r) * K + k0 + tx] = t[tx][r];
    }
}

// ---------------------------------------------------------------------------
// Scatter visible tokens + pos_embed. x f32 [8,1024,512]
// ---------------------------------------------------------------------------
__global__ __launch_bounds__(128)
void embed_k(const void* __restrict__ xv, const int* __restrict__ ids,
             const void* __restrict__ mtok, const void* __restrict__ pos,
             float* __restrict__ x, const int* __restrict__ bff)
{
    const int bf = bff[0];
    const int bid = blockIdx.x;
    const int p = bid & 1023, b = bid >> 10;
    const int* row = ids + b * 256;
    int lo = 0, hi = 256;
    while (lo < hi) { int mid = (lo + hi) >> 1; if (row[mid] <= p) lo = mid + 1; else hi = mid; }
    const int j = (lo > 0 && row[lo - 1] == p) ? (lo - 1) : -1;
    const int c = threadIdx.x * 4;
    const size_t sbase = (j >= 0) ? ((size_t)(b * 256 + j) * 512 + c) : (size_t)c;
    const void* srcp = (j >= 0) ? xv : mtok;
    const size_t o = (size_t)(b * 1024 + p) * 512 + c;
    #pragma unroll
    for (int e = 0; e < 4; ++e)
        x[o + e] = ldf(srcp, sbase + e, bf) + ldf(pos, (size_t)p * 512 + c + e, bf);
}

// ---------------------------------------------------------------------------
// RMSNorm over 512, f32 in -> bf16 out
// ---------------------------------------------------------------------------
__global__ __launch_bounds__(128)
void rms_k(const float* __restrict__ x, const void* __restrict__ w, int wo,
           u16* __restrict__ xn, const int* __restrict__ bff)
{
    const int bf = bff[0];
    const int row = blockIdx.x, tid = threadIdx.x;
    const float4 v = *reinterpret_cast<const float4*>(&x[(size_t)row * 512 + tid * 4]);
    float ss = v.x * v.x + v.y * v.y + v.z * v.z + v.w * v.w;
    #pragma unroll
    for (int off = 32; off >= 1; off >>= 1) ss += __shfl_xor(ss, off);
    __shared__ float sred[2];
    if ((tid & 63) == 0) sred[tid >> 6] = ss;
    __syncthreads();
    const float scale = rsqrtf((sred[0] + sred[1]) * (1.f / 512.f) + 1e-6f);
    const int c = tid * 4;
    u32 plo = f2b(v.x * scale * ldf(w, wo + c + 0, bf)) | ((u32)f2b(v.y * scale * ldf(w, wo + c + 1, bf)) << 16);
    u32 phi = f2b(v.z * scale * ldf(w, wo + c + 2, bf)) | ((u32)f2b(v.w * scale * ldf(w, wo + c + 3, bf)) << 16);
    uint2 pk; pk.x = plo; pk.y = phi;
    *reinterpret_cast<uint2*>(&xn[(size_t)row * 512 + c]) = pk;
}

// ---------------------------------------------------------------------------
// Causal depthwise conv (D_CONV=4) + bias + silu. bf16 in/out, f32 accum.
// ---------------------------------------------------------------------------
__global__ __launch_bounds__(256)
void conv_k(const u16* __restrict__ uz, const void* __restrict__ cw, int cwo,
            const void* __restrict__ cb, int cbo,
            u16* __restrict__ ucb, const int* __restrict__ bff)
{
    const int bf = bff[0];
    const int bid = blockIdx.x, tid = threadIdx.x;
    const int d = (bid & 3) * 256 + tid;
    const int lg = (bid >> 2) & 127;
    const int b = bid >> 9;
    const int l0 = lg * 8;
    const float w0 = ldf(cw, cwo + d * 4 + 0, bf), w1 = ldf(cw, cwo + d * 4 + 1, bf);
    const float w2 = ldf(cw, cwo + d * 4 + 2, bf), w3 = ldf(cw, cwo + d * 4 + 3, bf);
    const float bias = ldf(cb, cbo + d, bf);
    float u[11];
    #pragma unroll
    for (int j = 0; j < 11; ++j) {
        int l = l0 - 3 + j;
        u[j] = (l >= 0) ? b2f(uz[(size_t)(b * 1024 + l) * 2048 + d]) : 0.f;
    }
    #pragma unroll
    for (int i = 0; i < 8; ++i) {
        float a = bias + w0 * u[i] + w1 * u[i + 1] + w2 * u[i + 2] + w3 * u[i + 3];
        float s = a * (1.f / (1.f + __expf(-a)));
        ucb[(size_t)(b * 1024 + l0 + i) * 1024 + d] = f2b(s);
    }
}

// ===========================================================================
// Chunked selective scan (64 chunks x 16), 3 kernels (proven R13 structure):
//  scan1: local scan from h=0, y_loc = C.h_loc + u*D (bf16) + carry.
//  carry: in-place chunk-carry propagation (bf16 states).
//  scan2: correction: y = (y_loc + sum_s P_l[s]*h_in[s]*C_l[s]) * silu(z).
// Structured-A: P_l[s] = q_l^(s+1), one exp + power chains.
// ===========================================================================
__global__ __launch_bounds__(256)
void scan1_k(const u16* __restrict__ uz, const u16* __restrict__ ucb,
             const float* __restrict__ xdbl, const float* __restrict__ a2f, int alo,
             const float* __restrict__ df, int dso,
             u16* __restrict__ hcar, float* __restrict__ dtsum,
             u16* __restrict__ yloc, const int* __restrict__ astrp)
{
    const int tid = threadIdx.x;
    const int d = (blockIdx.x << 8) + tid;
    const int c = blockIdx.y, b = blockIdx.z;
    const int l0 = c * 16;
    const int astr = astrp[0];
    float h[16];
    #pragma unroll
    for (int s = 0; s < 16; ++s) h[s] = 0.f;
    const float* ap = &a2f[alo + d * 16];
    float A2[16];
    const float A2_0 = ap[0];
    if (!astr) {
        #pragma unroll
        for (int s = 0; s < 16; s += 4) {
            const float4 av = *reinterpret_cast<const float4*>(&ap[s]);
            A2[s] = av.x; A2[s+1] = av.y; A2[s+2] = av.z; A2[s+3] = av.w;
        }
    }
    const float Dv = df[dso + d];
    float dsum = 0.f;
    const u16* uzp = uz  + (size_t)(b * 1024 + l0) * 2048 + d;
    const u16* ucp = ucb + (size_t)(b * 1024 + l0) * 1024 + d;
    const float* xb = xdbl + (size_t)(b * 1024 + l0) * 64 + 32;
    u16* ylp = yloc + (size_t)(b * 1024 + l0) * 1024 + d;
    if (astr) {
        #pragma unroll 8
        for (int i = 0; i < 16; ++i) {
            float dtv = b2f(uzp[(size_t)i * 2048]);
            float uv  = b2f(ucp[(size_t)i * 1024]);
            float dtu = dtv * uv;
            dsum += dtv;
            const float4 B0 = *reinterpret_cast<const float4*>(xb + i * 64);
            const float4 B1 = *reinterpret_cast<const float4*>(xb + i * 64 + 4);
            const float4 B2 = *reinterpret_cast<const float4*>(xb + i * 64 + 8);
            const float4 B3 = *reinterpret_cast<const float4*>(xb + i * 64 + 12);
            const float4 C0 = *reinterpret_cast<const float4*>(xb + i * 64 + 16);
            const float4 C1 = *reinterpret_cast<const float4*>(xb + i * 64 + 20);
            const float4 C2 = *reinterpret_cast<const float4*>(xb + i * 64 + 24);
            const float4 C3 = *reinterpret_cast<const float4*>(xb + i * 64 + 28);
            const float Bv[16] = {B0.x,B0.y,B0.z,B0.w, B1.x,B1.y,B1.z,B1.w,
                                  B2.x,B2.y,B2.z,B2.w, B3.x,B3.y,B3.z,B3.w};
            const float Cv[16] = {C0.x,C0.y,C0.z,C0.w, C1.x,C1.y,C1.z,C1.w,
                                  C2.x,C2.y,C2.z,C2.w, C3.x,C3.y,C3.z,C3.w};
            float q  = exp2f(dtv * A2_0);
            float q2 = q * q, q3 = q2 * q, q4 = q2 * q2;
            float g1 = q, g2 = q2, g3 = q3, g4 = q4;
            float yv = 0.f;
            #pragma unroll
            for (int gr = 0; gr < 4; ++gr) {
                h[4*gr+0] = g1 * h[4*gr+0] + dtu * Bv[4*gr+0];
                h[4*gr+1] = g2 * h[4*gr+1] + dtu * Bv[4*gr+1];
                h[4*gr+2] = g3 * h[4*gr+2] + dtu * Bv[4*gr+2];
                h[4*gr+3] = g4 * h[4*gr+3] + dtu * Bv[4*gr+3];
                yv += h[4*gr+0] * Cv[4*gr+0] + h[4*gr+1] * Cv[4*gr+1]
                    + h[4*gr+2] * Cv[4*gr+2] + h[4*gr+3] * Cv[4*gr+3];
                if (gr < 3) { g1 *= q4; g2 *= q4; g3 *= q4; g4 *= q4; }
            }
            ylp[(size_t)i * 1024] = f2b(yv + uv * Dv);
        }
    } else {
        #pragma unroll 4
        for (int i = 0; i < 16; ++i) {
            float dtv = b2f(uzp[(size_t)i * 2048]);
            float uv  = b2f(ucp[(size_t)i * 1024]);
            float dtu = dtv * uv;
            dsum += dtv;
            const float4 B0 = *reinterpret_cast<const float4*>(xb + i * 64);
            const float4 B1 = *reinterpret_cast<const float4*>(xb + i * 64 + 4);
            const float4 B2 = *reinterpret_cast<const float4*>(xb + i * 64 + 8);
            const float4 B3 = *reinterpret_cast<const float4*>(xb + i * 64 + 12);
            const float4 C0 = *reinterpret_cast<const float4*>(xb + i * 64 + 16);
            const float4 C1 = *reinterpret_cast<const float4*>(xb + i * 64 + 20);
            const float4 C2 = *reinterpret_cast<const float4*>(xb + i * 64 + 24);
            const float4 C3 = *reinterpret_cast<const float4*>(xb + i * 64 + 28);
            const float Bv[16] = {B0.x,B0.y,B0.z,B0.w, B1.x,B1.y,B1.z,B1.w,
                                  B2.x,B2.y,B2.z,B2.w, B3.x,B3.y,B3.z,B3.w};
            const float Cv[16] = {C0.x,C0.y,C0.z,C0.w, C1.x,C1.y,C1.z,C1.w,
                                  C2.x,C2.y,C2.z,C2.w, C3.x,C3.y,C3.z,C3.w};
            float yv = 0.f;
            #pragma unroll
            for (int s = 0; s < 16; ++s) {
                h[s] = exp2f(dtv * A2[s]) * h[s] + dtu * Bv[s];
                yv += h[s] * Cv[s];
            }
            ylp[(size_t)i * 1024] = f2b(yv + uv * Dv);
        }
    }
    u16* hp = &hcar[((size_t)(b * 64 + c) * 1024 + d) * 16];
    #pragma unroll
    for (int s = 0; s < 16; s += 8) {
        uint4 pk;
        pk.x = f2b(h[s+0]) | ((u32)f2b(h[s+1]) << 16);
        pk.y = f2b(h[s+2]) | ((u32)f2b(h[s+3]) << 16);
        pk.z = f2b(h[s+4]) | ((u32)f2b(h[s+5]) << 16);
        pk.w = f2b(h[s+6]) | ((u32)f2b(h[s+7]) << 16);
        *reinterpret_cast<uint4*>(&hp[s]) = pk;
    }
    dtsum[(size_t)(b * 64 + c) * 1024 + d] = dsum;
}

__global__ __launch_bounds__(256)
void carry_k(u16* __restrict__ hcar, const float* __restrict__ dtsum,
             const float* __restrict__ a2f, int alo)
{
    const int t = blockIdx.x * 256 + threadIdx.x;   // (b, d, s)
    const int b = t >> 14;
    const int ds = t & 16383;
    const int d = ds >> 4;
    const float A2 = a2f[alo + ds];
    float h = 0.f;
    #pragma unroll 8
    for (int c = 0; c < 64; ++c) {
        const size_t idx = (size_t)(b * 64 + c) * 16384 + ds;
        const float hl = b2f(hcar[idx]);
        hcar[idx] = f2b(h);                          // entry state for scan2
        h = exp2f(A2 * dtsum[(size_t)(b * 64 + c) * 1024 + d]) * h + hl;
    }
}

__global__ __launch_bounds__(256)
void scan2_k(const u16* __restrict__ uz, const u16* __restrict__ yloc,
             const float* __restrict__ xdbl, const float* __restrict__ a2f, int alo,
             const u16* __restrict__ hcar, u16* __restrict__ y,
             const int* __restrict__ astrp)
{
    const int tid = threadIdx.x;
    const int d = (blockIdx.x << 8) + tid;
    const int c = blockIdx.y, b = blockIdx.z;
    const int l0 = c * 16;
    const int astr = astrp[0];
    float hs[16];
    const float* ap = &a2f[alo + d * 16];
    const u16* hp = &hcar[(size_t)(b * 64 + c) * 16384 + d * 16];
    const float A2_0 = ap[0];
    float A2[16];
    if (!astr) {
        #pragma unroll
        for (int s = 0; s < 16; s += 4) {
            const float4 av = *reinterpret_cast<const float4*>(&ap[s]);
            A2[s] = av.x; A2[s+1] = av.y; A2[s+2] = av.z; A2[s+3] = av.w;
        }
    }
    #pragma unroll
    for (int s = 0; s < 16; s += 8) {
        const uint4 pk = *reinterpret_cast<const uint4*>(&hp[s]);
        hs[s+0] = b2f((u16)(pk.x & 0xffff)); hs[s+1] = b2f((u16)(pk.x >> 16));
        hs[s+2] = b2f((u16)(pk.y & 0xffff)); hs[s+3] = b2f((u16)(pk.y >> 16));
        hs[s+4] = b2f((u16)(pk.z & 0xffff)); hs[s+5] = b2f((u16)(pk.z >> 16));
        hs[s+6] = b2f((u16)(pk.w & 0xffff)); hs[s+7] = b2f((u16)(pk.w >> 16));
    }
    const u16* uzp = uz   + (size_t)(b * 1024 + l0) * 2048 + d;
    const u16* ylp = yloc + (size_t)(b * 1024 + l0) * 1024 + d;
    const float* xb = xdbl + (size_t)(b * 1024 + l0) * 64 + 48;  // C cols only
    u16* yp_ = y + (size_t)(b * 1024 + l0) * 1024 + d;
    float S = 0.f;
    if (astr) {
        #pragma unroll 8
        for (int i = 0; i < 16; ++i) {
            float dtv = b2f(uzp[(size_t)i * 2048]);
            float zv  = b2f(uzp[(size_t)i * 2048 + 1024]);
            float ylv = b2f(ylp[(size_t)i * 1024]);
            S += dtv;
            const float4 C0 = *reinterpret_cast<const float4*>(xb + i * 64);
            const float4 C1 = *reinterpret_cast<const float4*>(xb + i * 64 + 4);
            const float4 C2 = *reinterpret_cast<const float4*>(xb + i * 64 + 8);
            const float4 C3 = *reinterpret_cast<const float4*>(xb + i * 64 + 12);
            const float Cv[16] = {C0.x,C0.y,C0.z,C0.w, C1.x,C1.y,C1.z,C1.w,
                                  C2.x,C2.y,C2.z,C2.w, C3.x,C3.y,C3.z,C3.w};
            float q  = exp2f(S * A2_0);
            float q2 = q * q, q3 = q2 * q, q4 = q2 * q2;
            float g1 = q, g2 = q2, g3 = q3, g4 = q4;
            float corr = 0.f;
            #pragma unroll
            for (int gr = 0; gr < 4; ++gr) {
                corr += (g1 * hs[4*gr+0]) * Cv[4*gr+0] + (g2 * hs[4*gr+1]) * Cv[4*gr+1]
                      + (g3 * hs[4*gr+2]) * Cv[4*gr+2] + (g4 * hs[4*gr+3]) * Cv[4*gr+3];
                if (gr < 3) { g1 *= q4; g2 *= q4; g3 *= q4; g4 *= q4; }
            }
            float yo = (ylv + corr) * (zv * (1.f / (1.f + __expf(-zv))));
            yp_[(size_t)i * 1024] = f2b(yo);
        }
    } else {
        #pragma unroll 4
        for (int i = 0; i < 16; ++i) {
            float dtv = b2f(uzp[(size_t)i * 2048]);
            float zv  = b2f(uzp[(size_t)i * 2048 + 1024]);
            float ylv = b2f(ylp[(size_t)i * 1024]);
            S += dtv;
            const float4 C0 = *reinterpret_cast<const float4*>(xb + i * 64);
            const float4 C1 = *reinterpret_cast<const float4*>(xb + i * 64 + 4);
            const float4 C2 = *reinterpret_cast<const float4*>(xb + i * 64 + 8);
            const float4 C3 = *reinterpret_cast<const float4*>(xb + i * 64 + 12);
            const float Cv[16] = {C0.x,C0.y,C0.z,C0.w, C1.x,C1.y,C1.z,C1.w,
                                  C2.x,C2.y,C2.z,C2.w, C3.x,C3.y,C3.z,C3.w};
            float corr = 0.f;
            #pragma unroll
            for (int s = 0; s < 16; ++s)
                corr += (exp2f(S * A2[s]) * hs[s]) * Cv[s];
            float yo = (ylv + corr) * (zv * (1.f / (1.f + __expf(-zv))));
            yp_[(size_t)i * 1024] = f2b(yo);
        }
    }
}

// ---------------------------------------------------------------------------
// Final RMSNorm + head GEMV (512 -> 16) + bias
// ---------------------------------------------------------------------------
__global__ __launch_bounds__(128)
void head_k(const float* __restrict__ x, const void* __restrict__ nw,
            const void* __restrict__ hw, const void* __restrict__ hb,
            void* __restrict__ out, const int* __restrict__ bff)
{
    const int bf = bff[0];
    const int row = blockIdx.x, tid = threadIdx.x;
    __shared__ float xs[512];
    __shared__ float pr[128];
    __shared__ float sred[2];
    const float4 v = *reinterpret_cast<const float4*>(&x[(size_t)row * 512 + tid * 4]);
    float ss = v.x * v.x + v.y * v.y + v.z * v.z + v.w * v.w;
    #pragma unroll
    for (int off = 32; off >= 1; off >>= 1) ss += __shfl_xor(ss, off);
    if ((tid & 63) == 0) sred[tid >> 6] = ss;
    __syncthreads();
    const float scale = rsqrtf((sred[0] + sred[1]) * (1.f / 512.f) + 1e-6f);
    const int c = tid * 4;
    xs[c + 0] = v.x * scale * ldf(nw, c + 0, bf);
    xs[c + 1] = v.y * scale * ldf(nw, c + 1, bf);
    xs[c + 2] = v.z * scale * ldf(nw, c + 2, bf);
    xs[c + 3] = v.w * scale * ldf(nw, c + 3, bf);
    __syncthreads();
    const int n = tid & 15, kg = tid >> 4;
    float s = 0.f;
    if (bf) {
        #pragma unroll 8
        for (int k = kg * 64; k < kg * 64 + 64; ++k)
            s += xs[k] * b2f(((const u16*)hw)[k * 16 + n]);
    } else {
        #pragma unroll 8
        for (int k = kg * 64; k < kg * 64 + 64; ++k)
            s += xs[k] * ((const float*)hw)[k * 16 + n];
    }
    pr[tid] = s;
    __syncthreads();
    if (tid < 16) {
        float a = ldf(hb, tid, bf);
        #pragma unroll
        for (int g = 0; g < 8; ++g) a += pr[g * 16 + tid];
        if (bf) ((u16*)out)[(size_t)row * 16 + tid] = f2b(a);
        else    ((float*)out)[(size_t)row * 16 + tid] = a;
    }
}

// ---------------------------------------------------------------------------
extern "C" void kernel_launch(void* const* d_in, const int* in_sizes, int n_in,
                              void* d_out, int out_size, void* d_ws, size_t ws_size,
                              hipStream_t stream)
{
    const void* xv   = d_in[0];
    const int*  ids  = (const int*)d_in[1];
    const void* mtok = d_in[2];
    const void* pos  = d_in[3];
    const void* inw  = d_in[4];
    const void* cw   = d_in[5];
    const void* cb   = d_in[6];
    const void* xpw  = d_in[7];
    const void* dtw  = d_in[8];
    const void* dtb  = d_in[9];
    const void* alog = d_in[10];
    const void* dsk  = d_in[11];
    const void* outw = d_in[12];
    const void* bnw  = d_in[13];
    const void* nw   = d_in[14];
    const void* hw   = d_in[15];
    const void* hb   = d_in[16];
    (void)in_sizes; (void)n_in; (void)out_size; (void)ws_size;

    char* base = (char*)d_ws;
    size_t off = 0;
    auto alloc = [&](size_t bytes) {
        char* p = base + off;
        off += (bytes + 255) & ~(size_t)255;
        return p;
    };
    int*   flag = (int*)  alloc(256);                  // [0]=dtype, [1]=A-structured
    float* x    = (float*)alloc(8192ull * 512 * 4);    // residual stream
    u16*   xn   = (u16*)  alloc(8192ull * 512 * 2);    // rmsnorm out (bf16)
    u16*   uzb  = (u16*)  alloc(8192ull * 2048 * 2);   // [u|z] bf16; u-half reused for dt
    u16*   ucb  = (u16*)  alloc(8192ull * 1024 * 2);   // conv+silu out bf16
    float* xdf  = (float*)alloc(8192ull * 64 * 4);     // x_dbl f32 (reduced)
    float* xdp  = (float*)alloc(4ull * 8192 * 64 * 4); // x_dbl split-K partials
    u16*   yb   = (u16*)  alloc(8192ull * 1024 * 2);   // gated y bf16
    u16*   ylb  = (u16*)  alloc(8192ull * 1024 * 2);   // local y (pre-gate) bf16
    u16*   wTin = (u16*)  alloc(4ull * 2048 * 512 * 2);
    u16*   wTxp = (u16*)  alloc(4ull * 64 * 1024 * 2);
    u16*   wTdt = (u16*)  alloc(4ull * 1024 * 32 * 2);
    u16*   wTout= (u16*)  alloc(4ull * 512 * 1024 * 2);
    float* dtsum= (float*)alloc(8ull * 64 * 1024 * 4);   // chunk carries: sum(dt)
    u16*   hcar = (u16*)  alloc(8ull * 64 * 16384 * 2);  // local sums -> entry states (bf16)
    float* a2f  = (float*)alloc(4ull * 16384 * 4);       // -exp(A_log)*log2e
    float* dff  = (float*)alloc(4ull * 1024 * 4);        // D_skip f32

    prep_k<<<256, 256, 0, stream>>>(alog, dsk, nw, a2f, dff, flag);

    // Transpose all layer weights to bf16 [N,K] once
    tr_k<<<dim3(2048 / 32, 512 / 32, 4), 256, 0, stream>>>(inw, wTin, 512, 2048, flag);
    tr_k<<<dim3(64 / 32, 1024 / 32, 4), 256, 0, stream>>>(xpw, wTxp, 1024, 64, flag);
    tr_k<<<dim3(1024 / 32, 32 / 32, 4), 256, 0, stream>>>(dtw, wTdt, 32, 1024, flag);
    tr_k<<<dim3(512 / 32, 1024 / 32, 4), 256, 0, stream>>>(outw, wTout, 1024, 512, flag);

    embed_k<<<8192, 128, 0, stream>>>(xv, ids, mtok, pos, x, flag);

    for (int i = 0; i < 4; ++i) {
        rms_k<<<8192, 128, 0, stream>>>(x, bnw, i * 512, xn, flag);
        // in_proj: [8192,512] @ [512,2048] -> uz bf16 (gld path, XCD-swizzled)
        gemm_gld_k<128, 0><<<dim3(16, 64), 256, 0, stream>>>(
            xn, 512, wTin + (size_t)i * 2048 * 512, 512, nullptr, 2048, uzb);
        conv_k<<<4096, 256, 0, stream>>>(uzb, cw, i * 4096, cb, i * 1024, ucb, flag);
        // x_proj: [8192,1024] @ [1024,64], split-K=4 -> partials
        gemm_k<64, 64, 64, 4, 4><<<dim3(4, 128), 256, 0, stream>>>(
            ucb, 1024, wTxp + (size_t)i * 64 * 1024, 1024, xdp, 64, nullptr,
            nullptr, 0, nullptr, 8192 * 64);
        xred_k<<<2048, 256, 0, stream>>>(xdp, xdf);
        // dt_proj: [8192,32] @ [32,1024] + bias -> fast softplus -> dt bf16
        gemm_k<64, 64, 32, 2, 1, 1><<<dim3(16, 128), 256, 0, stream>>>(
            (const u16*)xdf, 64, wTdt + (size_t)i * 1024 * 32, 32, nullptr, 2048, uzb,
            dtb, i * 1024, flag);
        // chunked scan: local scan + y_loc, carry, light correction (3 kernels)
        scan1_k<<<dim3(4, 64, 8), 256, 0, stream>>>(
            uzb, ucb, xdf, a2f, i * 16384, dff, i * 1024, hcar, dtsum, ylb, flag + 1);
        carry_k<<<512, 256, 0, stream>>>(hcar, dtsum, a2f, i * 16384);
        scan2_k<<<dim3(4, 64, 8), 256, 0, stream>>>(
            uzb, ylb, xdf, a2f, i * 16384, hcar, yb, flag + 1);
        // out_proj: [8192,1024] @ [1024,512] += residual x (gld path, XCD-swizzled)
        gemm_gld_k<64, 1><<<dim3(4, 128), 256, 0, stream>>>(
            yb, 1024, wTout + (size_t)i * 512 * 1024, 1024, x, 512, nullptr);
    }

    head_k<<<8192, 128, 0, stream>>>(x, nw, hw, hb, d_out, flag);
}